// Round 5
// baseline (15.194 us; speedup 1.0000x reference)
//
#include <hip/hip_runtime.h>

// STFT->iSTFT round trip with pinv-based synthesis kernel.
//
// Algebraic reduction (exact, not approximate):
//   inputs == out  (stack+concat is identity)
//   yfr = frames @ (weight^T @ inv_weight) ; weight = kernel*window,
//   inv_weight = pinv(kernel).T * window, and pinv(kernel)@kernel = I
//   (kernel is 514x512, full column rank) =>
//   yfr[b,t,k] = frames[b,t,k] * window[k]^2
//   overlap-add(yfr) == xp * coff  (identical index sets, term-by-term)
//   y = xp * coff/(coff+1e-8) ~= xp  (coff >= 1.25 on the kept slice)
//   y[:, PAD:-PAD] == x
//
// So the kernel is a pure copy: d_out <- d_in[0]. Memory roofline:
// 33.55 MB read + 33.55 MB write ~= 10.6 us at 6.3 TB/s achievable.
//
// R1: 1 float4/thread, 8192 blocks -> 15.3 us (4.4 TB/s).
// R2: 4 float4/thread ILP variant -> 25.2 us REGRESSION (reverted).
// R3: nontemporal hints — compile error (HIP_vector_type rejected).
// R4: nt with clang ext_vector_type -> 14.75 us (4.55 TB/s).
// R5: vendor blit via hipMemcpyAsync D2D (harness-sanctioned under graph
//     capture; rocclr fill kernels demonstrably sustain 80-85% peak).

extern "C" void kernel_launch(void* const* d_in, const int* in_sizes, int n_in,
                              void* d_out, int out_size, void* d_ws, size_t ws_size,
                              hipStream_t stream) {
    // out = x, exactly (see header). 33.55 MB device-to-device.
    hipMemcpyAsync(d_out, d_in[0], (size_t)out_size * sizeof(float),
                   hipMemcpyDeviceToDevice, stream);
}

// Round 6
// 14.046 us; speedup vs baseline: 1.0817x; 1.0817x over previous
//
#include <hip/hip_runtime.h>

// STFT->iSTFT round trip with pinv-based synthesis kernel.
//
// Algebraic reduction (exact, not approximate):
//   inputs == out  (stack+concat is identity)
//   yfr = frames @ (weight^T @ inv_weight) ; weight = kernel*window,
//   inv_weight = pinv(kernel).T * window, and pinv(kernel)@kernel = I
//   (kernel is 514x512, full column rank) =>
//   yfr[b,t,k] = frames[b,t,k] * window[k]^2
//   overlap-add(yfr) == xp * coff  (identical index sets, term-by-term)
//   y = xp * coff/(coff+1e-8) ~= xp  (coff >= 1.25 on the kept slice)
//   y[:, PAD:-PAD] == x
//
// So the kernel is a pure copy: d_out <- d_in[0].
//
// R1: 1 float4/thread, 8192 blocks -> 15.3 us (4.4 TB/s).
// R2: 4 float4/thread ILP variant -> 25.2 us REGRESSION (reverted).
// R3: nontemporal hints — compile error (HIP_vector_type rejected).
// R4: nt with clang ext_vector_type -> 14.75 us (4.55 TB/s).  <- best
// R5: vendor blit hipMemcpyAsync -> 15.19 us (no better than R4).
// R6: revert to R4. Three independent implementations (naive, nt, vendor
//     blit) converge at 14.7-15.3 us for this 33.5 MB D2D copy: the
//     residual vs the 10.6 us large-transfer analytic floor is ramp/drain
//     + launch overhead at this transfer size — structural. Roofline.

typedef float f32x4 __attribute__((ext_vector_type(4)));

__global__ __launch_bounds__(256) void stft_identity_copy_nt(
    const f32x4* __restrict__ in, f32x4* __restrict__ out, int n4) {
    int i = blockIdx.x * blockDim.x + threadIdx.x;
    if (i < n4) {
        f32x4 v = __builtin_nontemporal_load(&in[i]);
        __builtin_nontemporal_store(v, &out[i]);
    }
}

extern "C" void kernel_launch(void* const* d_in, const int* in_sizes, int n_in,
                              void* d_out, int out_size, void* d_ws, size_t ws_size,
                              hipStream_t stream) {
    const f32x4* x = (const f32x4*)d_in[0];  // (B=32, T=262144) f32, 16B-aligned
    f32x4* out = (f32x4*)d_out;              // same shape/dtype

    int n4 = out_size / 4;                   // 8,388,608 / 4 = 2,097,152 float4
    int block = 256;
    int grid = (n4 + block - 1) / block;     // 8192 blocks
    stft_identity_copy_nt<<<grid, block, 0, stream>>>(x, out, n4);
}